// Round 1
// baseline (1009.135 us; speedup 1.0000x reference)
//
#include <hip/hip_runtime.h>

// Problem constants (from reference): B=8, C=128, H=W=256, L=3, K=5, fp32.
#define BB 8
#define CC 128
#define HH 256
#define WW 256

// ---------------------------------------------------------------------------
// Forward level: fused Haar WT (stride-2, 2x2 butterfly) + depthwise 5x5 conv
// (SAME, zero-pad on subband domain) + per-band wscale.
//   in    : (B*C, H, W)
//   wconv : (4*C, 25)  for this level   (channel index c*4+k)
//   wsc   : (4*C)      for this level
//   tag   : (B*C, 4, H/2, W/2)          scaled conv output
//   rawLL : (B*C, H/2, W/2) or nullptr  raw LL band (input to next level)
// Block: 256 threads = 16x16 subband outputs; coeff halo tile 20x20x4 in LDS.
// ---------------------------------------------------------------------------
template <int H, int W>
__global__ __launch_bounds__(256) void fwd_level_kernel(
    const float* __restrict__ in,
    const float* __restrict__ wconv,
    const float* __restrict__ wsc,
    float* __restrict__ tag,
    float* __restrict__ rawLL)
{
    constexpr int hh = H / 2, ww = W / 2;
    const int bc  = blockIdx.z;          // b*C + c
    const int c   = bc % CC;
    const int ti0 = blockIdx.y * 16;     // subband tile origin (row)
    const int tj0 = blockIdx.x * 16;     // subband tile origin (col)
    const int tid = threadIdx.x;

    __shared__ float sb[4][20][20];      // 4 bands, 16+4 halo
    __shared__ float wg[4][25];
    __shared__ float wsl[4];

    if (tid < 100) {
        int k = tid / 25, t = tid % 25;
        wg[k][t] = wconv[(c * 4 + k) * 25 + t];
    }
    if (tid < 4) wsl[tid] = wsc[c * 4 + tid];

    const float* inb = in + (size_t)bc * H * W;

    // Compute 20x20 Haar coeffs (zero outside subband domain) into LDS.
    for (int idx = tid; idx < 400; idx += 256) {
        int r = idx / 20, q = idx % 20;
        int si = ti0 - 2 + r, sj = tj0 - 2 + q;
        float c0 = 0.f, c1 = 0.f, c2 = 0.f, c3 = 0.f;
        if (si >= 0 && si < hh && sj >= 0 && sj < ww) {
            const float* p = inb + (size_t)(2 * si) * W + 2 * sj;
            float x00 = p[0], x01 = p[1], x10 = p[W], x11 = p[W + 1];
            c0 = 0.5f * (x00 + x01 + x10 + x11);
            c1 = 0.5f * (x00 + x01 - x10 - x11);   // row-sign band (hi,lo)
            c2 = 0.5f * (x00 - x01 + x10 - x11);   // col-sign band (lo,hi)
            c3 = 0.5f * (x00 - x01 - x10 + x11);   // (hi,hi)
        }
        sb[0][r][q] = c0; sb[1][r][q] = c1; sb[2][r][q] = c2; sb[3][r][q] = c3;
    }
    __syncthreads();

    const int ty = tid / 16, tx = tid % 16;
    const int i = ti0 + ty, j = tj0 + tx;   // hh,ww are multiples of 16 -> in range

    float outv[4];
#pragma unroll
    for (int k = 0; k < 4; ++k) {
        float acc = 0.f;
#pragma unroll
        for (int u = 0; u < 5; ++u)
#pragma unroll
            for (int v = 0; v < 5; ++v)
                acc += sb[k][ty + u][tx + v] * wg[k][u * 5 + v];
        outv[k] = wsl[k] * acc;
    }

    const size_t plane = (size_t)hh * ww;
    const size_t tbase = (size_t)bc * 4 * plane + (size_t)i * ww + j;
#pragma unroll
    for (int k = 0; k < 4; ++k)
        tag[tbase + (size_t)k * plane] = outv[k];

    if (rawLL)
        rawLL[(size_t)bc * plane + (size_t)i * ww + j] = sb[0][ty + 2][tx + 2];
}

// ---------------------------------------------------------------------------
// Inverse Haar: up[2i+a][2j+b] = 0.5*(c0' + sa*c1 + sb*c2 + sa*sb*c3)
// with c0' = tag LL + prev (upsampled LL from level below), prev may be null.
//   tag  : (B*C, 4, hh, ww)
//   prev : (B*C, hh, ww) or nullptr
//   up   : (B*C, 2hh, 2ww)
// ---------------------------------------------------------------------------
template <int hh, int ww>
__global__ __launch_bounds__(256) void iwt_kernel(
    const float* __restrict__ tag,
    const float* __restrict__ prev,
    float* __restrict__ up)
{
    const int n = BB * CC * hh * ww;
    int gid = blockIdx.x * blockDim.x + threadIdx.x;
    if (gid >= n) return;
    const int j  = gid % ww;
    const int i  = (gid / ww) % hh;
    const int bc = gid / (ww * hh);
    const size_t plane = (size_t)hh * ww;
    const size_t base  = (size_t)bc * 4 * plane + (size_t)i * ww + j;

    float c0 = tag[base];
    if (prev) c0 += prev[gid];
    const float c1 = tag[base + plane];
    const float c2 = tag[base + 2 * plane];
    const float c3 = tag[base + 3 * plane];

    const float o00 = 0.5f * (c0 + c1 + c2 + c3);
    const float o01 = 0.5f * (c0 + c1 - c2 - c3);
    const float o10 = 0.5f * (c0 - c1 + c2 - c3);
    const float o11 = 0.5f * (c0 - c1 - c2 + c3);

    float* ub = up + (size_t)bc * 4 * plane;
    float2* r0 = (float2*)(ub + (size_t)(2 * i) * (2 * ww) + 2 * j);
    float2* r1 = (float2*)(ub + (size_t)(2 * i + 1) * (2 * ww) + 2 * j);
    *r0 = make_float2(o00, o01);
    *r1 = make_float2(o10, o11);
}

// ---------------------------------------------------------------------------
// Final: out = base_scale*(dw5x5(x)+base_b) + iwt0(tag0 with LL += ll1up)
// Block: 256 threads -> 32x32 output tile for one (b,c); x tile 36x36 in LDS,
// level-0 coeff tile 16x16x4 (LL pre-combined with ll1up) in LDS.
// ---------------------------------------------------------------------------
__global__ __launch_bounds__(256) void final_kernel(
    const float* __restrict__ x,          // (B*C, 256, 256)
    const float* __restrict__ tag0,       // (B*C, 4, 128, 128)
    const float* __restrict__ ll1,        // (B*C, 128, 128)
    const float* __restrict__ base_w,     // (C, 25)
    const float* __restrict__ base_b,     // (C)
    const float* __restrict__ base_scale, // (C)
    float* __restrict__ out)              // (B*C, 256, 256)
{
    const int bc  = blockIdx.z;
    const int c   = bc % CC;
    const int tY0 = blockIdx.y * 32, tX0 = blockIdx.x * 32;
    const int tid = threadIdx.x;

    __shared__ float sx[36][36];
    __shared__ float sc[4][16][16];
    __shared__ float wg[25];
    __shared__ float sbias, sscale;

    if (tid < 25) wg[tid] = base_w[c * 25 + tid];
    if (tid == 0) { sbias = base_b[c]; sscale = base_scale[c]; }

    const float* xb = x + (size_t)bc * HH * WW;
    for (int idx = tid; idx < 36 * 36; idx += 256) {
        int r = idx / 36, q = idx % 36;
        int Y = tY0 - 2 + r, X = tX0 - 2 + q;
        sx[r][q] = (Y >= 0 && Y < HH && X >= 0 && X < WW)
                       ? xb[(size_t)Y * WW + X] : 0.f;
    }

    const int ci0 = tY0 >> 1, cj0 = tX0 >> 1;
    const size_t cplane = (size_t)128 * 128;
    const size_t cbase  = (size_t)bc * 4 * cplane;
    for (int idx = tid; idx < 4 * 256; idx += 256) {
        int k = idx >> 8, r = (idx >> 4) & 15, q = idx & 15;
        size_t o = (size_t)(ci0 + r) * 128 + (cj0 + q);
        float v = tag0[cbase + (size_t)k * cplane + o];
        if (k == 0) v += ll1[(size_t)bc * cplane + o];
        sc[k][r][q] = v;
    }
    __syncthreads();

    const int ty = tid >> 5, tx = tid & 31;   // 8 x 32
    float* ob = out + (size_t)bc * HH * WW;
#pragma unroll
    for (int rr = 0; rr < 4; ++rr) {
        const int ly = ty + 8 * rr;           // local row 0..31
        const int Y = tY0 + ly, X = tX0 + tx;

        float acc = 0.f;
#pragma unroll
        for (int u = 0; u < 5; ++u)
#pragma unroll
            for (int v = 0; v < 5; ++v)
                acc += sx[ly + u][tx + v] * wg[u * 5 + v];
        const float base = sscale * (acc + sbias);

        const int cy = ly >> 1, cx = tx >> 1;
        const float sa = (ly & 1) ? -1.f : 1.f;
        const float sb = (tx & 1) ? -1.f : 1.f;
        const float c0 = sc[0][cy][cx], c1 = sc[1][cy][cx];
        const float c2 = sc[2][cy][cx], c3 = sc[3][cy][cx];
        const float w = 0.5f * (c0 + sa * c1 + sb * c2 + sa * sb * c3);

        ob[(size_t)Y * WW + X] = base + w;
    }
}

// ---------------------------------------------------------------------------
extern "C" void kernel_launch(void* const* d_in, const int* in_sizes, int n_in,
                              void* d_out, int out_size, void* d_ws, size_t ws_size,
                              hipStream_t stream)
{
    const float* x          = (const float*)d_in[0];
    // d_in[1] wt_filter, d_in[2] iwt_filter: fixed Haar, hard-coded above.
    const float* base_w     = (const float*)d_in[3];
    const float* base_b     = (const float*)d_in[4];
    const float* base_scale = (const float*)d_in[5];
    const float* wconv      = (const float*)d_in[6];  // (3, 512, 25)
    const float* wscale     = (const float*)d_in[7];  // (3, 512)
    float* out = (float*)d_out;
    float* ws  = (float*)d_ws;

    // Workspace layout (floats):
    float* tag0 = ws;                    // 8*128*4*128*128 = 67,108,864
    float* tag1 = ws + 67108864;         // 8*128*4*64*64   = 16,777,216
    float* tag2 = ws + 83886080;         // 8*128*4*32*32   =  4,194,304
    float* bufA = ws + 88080384;         // 16,777,216 : rawLL0, then ll1up
    float* bufB = ws + 104857600;        //  4,194,304 : rawLL1, then ll2up
    // total 109,051,904 floats = 416 MiB

    const dim3 blk(256);
    const int BC = BB * CC;

    // Forward: level 0,1,2  (WT + depthwise conv + wscale fused)
    fwd_level_kernel<256, 256><<<dim3(8, 8, BC), blk, 0, stream>>>(
        x, wconv, wscale, tag0, bufA);
    fwd_level_kernel<128, 128><<<dim3(4, 4, BC), blk, 0, stream>>>(
        bufA, wconv + 512 * 25, wscale + 512, tag1, bufB);
    fwd_level_kernel<64, 64><<<dim3(2, 2, BC), blk, 0, stream>>>(
        bufB, wconv + 2 * 512 * 25, wscale + 2 * 512, tag2, nullptr);

    // Inverse: level 2 -> ll2up (reuse bufB), level 1 -> ll1up (reuse bufA)
    {
        const int n = BC * 32 * 32;
        iwt_kernel<32, 32><<<dim3((n + 255) / 256), blk, 0, stream>>>(
            tag2, nullptr, bufB);
    }
    {
        const int n = BC * 64 * 64;
        iwt_kernel<64, 64><<<dim3((n + 255) / 256), blk, 0, stream>>>(
            tag1, bufB, bufA);
    }

    // Final: base conv + level-0 inverse WT, fused.
    final_kernel<<<dim3(8, 8, BC), blk, 0, stream>>>(
        x, tag0, bufA, base_w, base_b, base_scale, out);
}